// Round 2
// baseline (212.384 us; speedup 1.0000x reference)
//
#include <hip/hip_runtime.h>
#include <cstdint>
#include <cstddef>

// ---------------------------------------------------------------------------
// Style2ResidualBlock1DSrc: modulated conv1d (StyleGAN2-style) on MI355X.
// bf16 MFMA GEMM pipeline: style GEMV -> modulate/demod weights (bf16) ->
// transpose+pad x to [t][i] bf16 -> 3-tap accumulating GEMM per batch.
// R1: fast transpose (16B/lane both ways), block-per-o modw, wave-coop style,
//     gemm __launch_bounds__(256,4) (was (256,2) — capped occupancy at 31%).
// ---------------------------------------------------------------------------

#define LIN_SCALE  0.0625f           // 1/sqrt(256)
#define CONV_SCALE 0.014731391f      // 1/sqrt(512*9)

#define B_   16
#define CIN  512
#define COUT 512
#define T_   2048
#define TP   2050                    // T + 2 pad rows

typedef __bf16 bf16x8 __attribute__((ext_vector_type(8)));
typedef float  f32x4  __attribute__((ext_vector_type(4)));
typedef unsigned short u16x8 __attribute__((ext_vector_type(8)));
typedef unsigned short u16x2 __attribute__((ext_vector_type(2)));

__device__ inline unsigned short f2bf(float f) {
  __bf16 h = (__bf16)f;              // RNE fptrunc
  return __builtin_bit_cast(unsigned short, h);
}

// ---------------- 1. style linear: s[b][i] ----------------
// grid (8 i-blocks, 16 b), 256 threads = 4 waves; wave handles 16 rows,
// lanes cover j coalesced (256B per load), shuffle reduce.
__global__ __launch_bounds__(256) void style_kernel(const float* __restrict__ c_src,
                                                    const float* __restrict__ c_trg,
                                                    const float* __restrict__ sw,
                                                    const float* __restrict__ sb,
                                                    float* __restrict__ s) {
  __shared__ float c[256];
  const int b = blockIdx.y;
  const int tid = threadIdx.x;
  c[tid] = (tid < 128) ? c_src[b * 128 + tid] : c_trg[b * 128 + tid - 128];
  __syncthreads();
  const int w = tid >> 6, lane = tid & 63;
  #pragma unroll
  for (int rr = 0; rr < 16; ++rr) {
    const int i = blockIdx.x * 64 + w * 16 + rr;
    const float* row = sw + (size_t)i * 256;
    float acc = row[lane] * c[lane] + row[lane + 64] * c[lane + 64]
              + row[lane + 128] * c[lane + 128] + row[lane + 192] * c[lane + 192];
    #pragma unroll
    for (int off = 32; off; off >>= 1) acc += __shfl_down(acc, off, 64);
    if (lane == 0) s[b * 512 + i] = acc * LIN_SCALE + sb[i];
  }
}

// ---------------- 2. modulate + demodulate -> bf16 W[b][tap][o][i] ----------------
// One block per o (512 blocks). Weight row + all of s staged in LDS once;
// loop over b with one shuffle-reduce + 2 barriers total.
__global__ __launch_bounds__(256) void modw_kernel(const float* __restrict__ weight,
                                                   const float* __restrict__ s,
                                                   unsigned short* __restrict__ Wm) {
  const int o = blockIdx.x;
  const int tid = threadIdx.x;
  __shared__ float wsh[1536];        // weight[o][:][:]
  __shared__ float svs[16 * 512];    // all style vectors (32 KB)
  __shared__ float partial[16][4];
  __shared__ float demv[16];

  #pragma unroll
  for (int j = tid; j < 1536; j += 256) wsh[j] = weight[(size_t)o * 1536 + j];
  #pragma unroll
  for (int j = tid; j < 16 * 512; j += 256) svs[j] = s[j];
  __syncthreads();

  // thread covers i = 2*tid, 2*tid+1; wsh[tid*6+q] = weight[o][i][k], q=3*(i&1)+k
  float wr[6];
  #pragma unroll
  for (int q = 0; q < 6; ++q) wr[q] = wsh[tid * 6 + q] * CONV_SCALE;

  const int lane = tid & 63, w = tid >> 6;
  float ssb[16];
  #pragma unroll
  for (int b = 0; b < 16; ++b) {
    const float s0 = svs[b * 512 + 2 * tid];
    const float s1 = svs[b * 512 + 2 * tid + 1];
    float ss = 0.f;
    #pragma unroll
    for (int q = 0; q < 3; ++q) { float v = wr[q] * s0;     ss += v * v; }
    #pragma unroll
    for (int q = 3; q < 6; ++q) { float v = wr[q] * s1;     ss += v * v; }
    ssb[b] = ss;
  }
  #pragma unroll
  for (int b = 0; b < 16; ++b) {
    float ss = ssb[b];
    #pragma unroll
    for (int off = 32; off; off >>= 1) ss += __shfl_down(ss, off, 64);
    if (lane == 0) partial[b][w] = ss;
  }
  __syncthreads();
  if (tid < 16)
    demv[tid] = rsqrtf(partial[tid][0] + partial[tid][1] + partial[tid][2] + partial[tid][3] + 1e-8f);
  __syncthreads();

  #pragma unroll
  for (int b = 0; b < 16; ++b) {
    const float dem = demv[b];
    const float s0 = svs[b * 512 + 2 * tid] * dem;
    const float s1 = svs[b * 512 + 2 * tid + 1] * dem;
    #pragma unroll
    for (int k = 0; k < 3; ++k) {
      u16x2 v;
      v.x = f2bf(wr[k] * s0);
      v.y = f2bf(wr[3 + k] * s1);
      *(u16x2*)&Wm[(((size_t)b * 3 + k) * 512 + o) * 512 + 2 * tid] = v;
    }
  }
}

// ---------------- 3. transpose + pad + bf16: xT[b][1+t][i] = x[b][i][t] ----------------
// 64x64 tile; float4 loads (16B/lane), LDS [64][65] fp32 (write: 2-way free;
// transposed read: 2-way free by 65-stride bank math), bf16x8 stores (16B/lane).
__global__ __launch_bounds__(256) void transpose_kernel(const float* __restrict__ x,
                                                        unsigned short* __restrict__ xT) {
  __shared__ float tile[64][65];
  const int b = blockIdx.z, i0 = blockIdx.y * 64, t0 = blockIdx.x * 64;
  const int tid = threadIdx.x;

  const int lr = tid >> 4;            // 0..15 row within pass
  const int lc = (tid & 15) * 4;      // t offset (float4)
  const float* xb = x + ((size_t)b * CIN + i0) * T_ + t0;
  #pragma unroll
  for (int p = 0; p < 4; ++p) {
    const int r = p * 16 + lr;
    const float4 v = *(const float4*)(xb + (size_t)r * T_ + lc);
    tile[r][lc + 0] = v.x; tile[r][lc + 1] = v.y;
    tile[r][lc + 2] = v.z; tile[r][lc + 3] = v.w;
  }
  __syncthreads();

  const int st = tid >> 3;            // 0..31 t-row within pass
  const int si = (tid & 7) * 8;       // i offset (8 ushorts = 16B)
  unsigned short* xTb = xT + ((size_t)b * TP + 1 + t0) * CIN + i0;
  #pragma unroll
  for (int p = 0; p < 2; ++p) {
    const int t = p * 32 + st;
    u16x8 v;
    #pragma unroll
    for (int q = 0; q < 8; ++q) v[q] = f2bf(tile[si + q][t]);
    *(u16x8*)&xTb[(size_t)t * CIN + si] = v;
  }
}

// zero pad rows t=0 and t=2049 of xT
__global__ void zpad_kernel(unsigned short* __restrict__ xT) {
  const int b = blockIdx.x;
  const size_t base = (size_t)b * TP * CIN;
  for (int j = threadIdx.x; j < CIN; j += 256) {
    xT[base + j] = 0;
    xT[base + (size_t)(TP - 1) * CIN + j] = 0;
  }
}

// ---------------- 4. main GEMM: out[b][o][t] = sum_tap W_tap @ xT(shifted) ----------------
// 128x128 tile, BK=64, 256 threads = 4 waves, each wave 64x64 (4x4 MFMA 16x16x32 frags).
// launch_bounds(256,4): 4 blocks/CU (LDS 4x32=128KB<=160, VGPR 60<=128).
#define BM 128
#define BN 128
#define BK 64

__global__ __launch_bounds__(256, 4) void gemm_kernel(const unsigned short* __restrict__ Wm,
                                                      const unsigned short* __restrict__ xT,
                                                      float* __restrict__ out) {
  __shared__ unsigned short lA[BM * BK];   // 16 KB: A tile [o_row][i]
  __shared__ unsigned short lB[BN * BK];   // 16 KB: B tile [t_row][i]

  const int b  = blockIdx.z;
  const int o0 = blockIdx.y * BM;
  const int t0 = blockIdx.x * BN;
  const int tid  = threadIdx.x;
  const int lane = tid & 63;
  const int wm = (threadIdx.x >> 6 & 1) * 64;   // wave row (o) offset
  const int wn = (threadIdx.x >> 7) * 64;       // wave col (t) offset

  // staging: thread -> 16B chunk; round p adds 32 rows
  const int srow = tid >> 3;           // 0..31
  const int scol = (tid & 7) * 8;      // element offset within 64-wide row
  const unsigned short* gW = Wm + (size_t)b * 3 * 512 * 512 + (size_t)(o0 + srow) * 512 + scol;
  const unsigned short* gX = xT + (size_t)b * TP * CIN + (size_t)(t0 + srow) * CIN + scol;
  unsigned short* lAp = &lA[tid * 8];  // dest chunk, lane-contiguous within wave
  unsigned short* lBp = &lB[tid * 8];

  f32x4 acc[4][4];
  #pragma unroll
  for (int i = 0; i < 4; ++i)
    #pragma unroll
    for (int j = 0; j < 4; ++j) acc[i][j] = (f32x4){0.f, 0.f, 0.f, 0.f};

  for (int kk = 0; kk < 24; ++kk) {
    const int tap = kk >> 3;
    const int i0  = (kk & 7) * 64;
    const size_t offA = (size_t)tap * 512 * 512 + i0;   // W tap plane + i block
    const size_t offX = (size_t)tap * CIN + i0;          // t shift = tap rows + i block
    __syncthreads();                    // LDS reuse: previous compute done
    #pragma unroll
    for (int p = 0; p < 4; ++p)
      __builtin_amdgcn_global_load_lds(
          (const __attribute__((address_space(1))) void*)(gW + offA + (size_t)p * 32 * 512),
          (__attribute__((address_space(3))) void*)(lAp + p * 2048), 16, 0, 0);
    #pragma unroll
    for (int p = 0; p < 4; ++p)
      __builtin_amdgcn_global_load_lds(
          (const __attribute__((address_space(1))) void*)(gX + offX + (size_t)p * 32 * CIN),
          (__attribute__((address_space(3))) void*)(lBp + p * 2048), 16, 0, 0);
    __syncthreads();                    // staging visible (implies vmcnt(0))

    #pragma unroll
    for (int s = 0; s < 2; ++s) {
      const int ko = s * 32 + (lane >> 4) * 8;
      bf16x8 af[4], bfr[4];
      #pragma unroll
      for (int mi = 0; mi < 4; ++mi)
        af[mi] = *(const bf16x8*)&lA[(wm + mi * 16 + (lane & 15)) * BK + ko];
      #pragma unroll
      for (int ni = 0; ni < 4; ++ni)
        bfr[ni] = *(const bf16x8*)&lB[(wn + ni * 16 + (lane & 15)) * BK + ko];
      #pragma unroll
      for (int mi = 0; mi < 4; ++mi)
        #pragma unroll
        for (int ni = 0; ni < 4; ++ni)
          acc[mi][ni] = __builtin_amdgcn_mfma_f32_16x16x32_bf16(af[mi], bfr[ni], acc[mi][ni], 0, 0, 0);
    }
  }

  // epilogue: D row = (lane>>4)*4 + reg, col = lane&15  (m89 mapping)
  float* ob = out + ((size_t)b * COUT + o0 + wm) * T_ + t0 + wn;
  const int rrow = (lane >> 4) * 4;
  const int ccol = lane & 15;
  #pragma unroll
  for (int mi = 0; mi < 4; ++mi)
    #pragma unroll
    for (int ni = 0; ni < 4; ++ni)
      #pragma unroll
      for (int r = 0; r < 4; ++r)
        ob[(size_t)(mi * 16 + rrow + r) * T_ + ni * 16 + ccol] = acc[mi][ni][r];
}

// ---------------------------------------------------------------------------
extern "C" void kernel_launch(void* const* d_in, const int* in_sizes, int n_in,
                              void* d_out, int out_size, void* d_ws, size_t ws_size,
                              hipStream_t stream) {
  const float* x       = (const float*)d_in[0];   // [16,512,2048]
  const float* c_src   = (const float*)d_in[1];   // [16,128]
  const float* c_trg   = (const float*)d_in[2];   // [16,128]
  const float* style_w = (const float*)d_in[3];   // [512,256]
  const float* style_b = (const float*)d_in[4];   // [512]
  const float* weight  = (const float*)d_in[5];   // [1,512,512,3]
  float* out = (float*)d_out;

  // workspace layout:
  //   s_buf  fp32 [16][512]            @ 0        (32 KB)
  //   Wm     bf16 [16][3][512][512]    @ 32768    (25,165,824 B)
  //   xT     bf16 [16][2050][512]      @ 25198592 (33,587,200 B)
  char* ws = (char*)d_ws;
  float* s_buf          = (float*)ws;
  unsigned short* Wm    = (unsigned short*)(ws + 32768);
  unsigned short* xTbuf = (unsigned short*)(ws + 32768 + 25165824);

  style_kernel<<<dim3(8, 16), 256, 0, stream>>>(c_src, c_trg, style_w, style_b, s_buf);
  modw_kernel<<<dim3(COUT), 256, 0, stream>>>(weight, s_buf, Wm);
  transpose_kernel<<<dim3(T_ / 64, CIN / 64, B_), 256, 0, stream>>>(x, xTbuf);
  zpad_kernel<<<dim3(B_), 256, 0, stream>>>(xTbuf);
  gemm_kernel<<<dim3(T_ / BN, COUT / BM, B_), 256, 0, stream>>>(Wm, xTbuf, out);
}

// Round 3
// 188.938 us; speedup vs baseline: 1.1241x; 1.1241x over previous
//
#include <hip/hip_runtime.h>
#include <cstdint>
#include <cstddef>

// ---------------------------------------------------------------------------
// Style2ResidualBlock1DSrc: modulated conv1d (StyleGAN2-style) on MI355X.
// bf16 MFMA GEMM pipeline. R2:
//  - gemm: tap-fused K-loop (stage B once per i-block for all 3 taps;
//    96 MFMA/wave per barrier-pair vs 32), BM=64 BN=256 BK=64.
//  - gemm: XOR-swizzled LDS tiles (kills the measured 1.9e7 bank conflicts:
//    row stride 128B put all 16 frag-read lanes on one bank quad).
//  - gemm: XCD b-grouping (ids == b mod 8 -> Wm[b]+xT[b] = 3.7MB fits one L2).
//  - zpad fused into transpose.
// ---------------------------------------------------------------------------

#define LIN_SCALE  0.0625f           // 1/sqrt(256)
#define CONV_SCALE 0.014731391f      // 1/sqrt(512*9)

#define B_   16
#define CIN  512
#define COUT 512
#define T_   2048
#define TP   2050                    // T + 2 pad rows

typedef __bf16 bf16x8 __attribute__((ext_vector_type(8)));
typedef float  f32x4  __attribute__((ext_vector_type(4)));
typedef unsigned short u16x8 __attribute__((ext_vector_type(8)));
typedef unsigned short u16x2 __attribute__((ext_vector_type(2)));

__device__ inline unsigned short f2bf(float f) {
  __bf16 h = (__bf16)f;              // RNE fptrunc
  return __builtin_bit_cast(unsigned short, h);
}

// ---------------- 1. style linear: s[b][i] ----------------
__global__ __launch_bounds__(256) void style_kernel(const float* __restrict__ c_src,
                                                    const float* __restrict__ c_trg,
                                                    const float* __restrict__ sw,
                                                    const float* __restrict__ sb,
                                                    float* __restrict__ s) {
  __shared__ float c[256];
  const int b = blockIdx.y;
  const int tid = threadIdx.x;
  c[tid] = (tid < 128) ? c_src[b * 128 + tid] : c_trg[b * 128 + tid - 128];
  __syncthreads();
  const int w = tid >> 6, lane = tid & 63;
  #pragma unroll
  for (int rr = 0; rr < 16; ++rr) {
    const int i = blockIdx.x * 64 + w * 16 + rr;
    const float* row = sw + (size_t)i * 256;
    float acc = row[lane] * c[lane] + row[lane + 64] * c[lane + 64]
              + row[lane + 128] * c[lane + 128] + row[lane + 192] * c[lane + 192];
    #pragma unroll
    for (int off = 32; off; off >>= 1) acc += __shfl_down(acc, off, 64);
    if (lane == 0) s[b * 512 + i] = acc * LIN_SCALE + sb[i];
  }
}

// ---------------- 2. modulate + demodulate -> bf16 W[b][tap][o][i] ----------------
__global__ __launch_bounds__(256) void modw_kernel(const float* __restrict__ weight,
                                                   const float* __restrict__ s,
                                                   unsigned short* __restrict__ Wm) {
  const int o = blockIdx.x;
  const int tid = threadIdx.x;
  __shared__ float wsh[1536];        // weight[o][:][:]
  __shared__ float svs[16 * 512];    // all style vectors (32 KB)
  __shared__ float partial[16][4];
  __shared__ float demv[16];

  #pragma unroll
  for (int j = tid; j < 1536; j += 256) wsh[j] = weight[(size_t)o * 1536 + j];
  #pragma unroll
  for (int j = tid; j < 16 * 512; j += 256) svs[j] = s[j];
  __syncthreads();

  float wr[6];
  #pragma unroll
  for (int q = 0; q < 6; ++q) wr[q] = wsh[tid * 6 + q] * CONV_SCALE;

  const int lane = tid & 63, w = tid >> 6;
  float ssb[16];
  #pragma unroll
  for (int b = 0; b < 16; ++b) {
    const float s0 = svs[b * 512 + 2 * tid];
    const float s1 = svs[b * 512 + 2 * tid + 1];
    float ss = 0.f;
    #pragma unroll
    for (int q = 0; q < 3; ++q) { float v = wr[q] * s0; ss += v * v; }
    #pragma unroll
    for (int q = 3; q < 6; ++q) { float v = wr[q] * s1; ss += v * v; }
    ssb[b] = ss;
  }
  #pragma unroll
  for (int b = 0; b < 16; ++b) {
    float ss = ssb[b];
    #pragma unroll
    for (int off = 32; off; off >>= 1) ss += __shfl_down(ss, off, 64);
    if (lane == 0) partial[b][w] = ss;
  }
  __syncthreads();
  if (tid < 16)
    demv[tid] = rsqrtf(partial[tid][0] + partial[tid][1] + partial[tid][2] + partial[tid][3] + 1e-8f);
  __syncthreads();

  #pragma unroll
  for (int b = 0; b < 16; ++b) {
    const float dem = demv[b];
    const float s0 = svs[b * 512 + 2 * tid] * dem;
    const float s1 = svs[b * 512 + 2 * tid + 1] * dem;
    #pragma unroll
    for (int k = 0; k < 3; ++k) {
      u16x2 v;
      v.x = f2bf(wr[k] * s0);
      v.y = f2bf(wr[3 + k] * s1);
      *(u16x2*)&Wm[(((size_t)b * 3 + k) * 512 + o) * 512 + 2 * tid] = v;
    }
  }
}

// ---------------- 3. transpose + pad + bf16 (+ fused zpad) ----------------
__global__ __launch_bounds__(256) void transpose_kernel(const float* __restrict__ x,
                                                        unsigned short* __restrict__ xT) {
  __shared__ float tile[64][65];
  const int b = blockIdx.z, i0 = blockIdx.y * 64, t0 = blockIdx.x * 64;
  const int tid = threadIdx.x;

  const int lr = tid >> 4;            // 0..15
  const int lc = (tid & 15) * 4;      // float4
  const float* xb = x + ((size_t)b * CIN + i0) * T_ + t0;
  #pragma unroll
  for (int p = 0; p < 4; ++p) {
    const int r = p * 16 + lr;
    const float4 v = *(const float4*)(xb + (size_t)r * T_ + lc);
    tile[r][lc + 0] = v.x; tile[r][lc + 1] = v.y;
    tile[r][lc + 2] = v.z; tile[r][lc + 3] = v.w;
  }
  // fused zero-pad of rows 0 and 2049 (no barrier dependency)
  if (blockIdx.x == 0 && tid < 8)
    *(u16x8*)&xT[(size_t)b * TP * CIN + i0 + tid * 8] = (u16x8){0,0,0,0,0,0,0,0};
  if (blockIdx.x == gridDim.x - 1 && tid < 8)
    *(u16x8*)&xT[((size_t)b * TP + TP - 1) * CIN + i0 + tid * 8] = (u16x8){0,0,0,0,0,0,0,0};
  __syncthreads();

  const int st = tid >> 3;            // 0..31
  const int si = (tid & 7) * 8;       // 16B
  unsigned short* xTb = xT + ((size_t)b * TP + 1 + t0) * CIN + i0;
  #pragma unroll
  for (int p = 0; p < 2; ++p) {
    const int t = p * 32 + st;
    u16x8 v;
    #pragma unroll
    for (int q = 0; q < 8; ++q) v[q] = f2bf(tile[si + q][t]);
    *(u16x8*)&xTb[(size_t)t * CIN + si] = v;
  }
}

// ---------------- 4. main GEMM, tap-fused ----------------
// out[b][o0+..64][t0+..256] = sum_{tap,i} Wm[b][tap][o][i] * xT[b][t0+lt+tap][i]
// LDS: lA[3][64][64] xor-swizzled, lB[258][64] xor-swizzled. 57.6 KB -> 2 blk/CU.
// 4 waves, each 64(M) x 64(N) via 4x4 16x16x32 frags; accs accumulate over taps.
#define BM 64
#define BN 256
#define BK 64

__global__ __launch_bounds__(256, 2) void gemm_kernel(const unsigned short* __restrict__ Wm,
                                                      const unsigned short* __restrict__ xT,
                                                      float* __restrict__ out) {
  __shared__ unsigned short lA[3 * 64 * 64];   // 24576 B
  __shared__ unsigned short lB[258 * 64];      // 33024 B

  // XCD b-grouping: ids == b (mod 8) -> all 64 blocks of a batch on one XCD.
  const int id  = blockIdx.x;
  const int xcd = id & 7;
  const int j   = id >> 3;                 // 0..127
  const int b   = xcd + 8 * (j >> 6);      // 0..15
  const int r   = j & 63;
  const int o0  = (r >> 3) * BM;           // 8 o-blocks
  const int t0  = (r & 7) * BN;            // 8 t-blocks

  const int tid  = threadIdx.x;
  const int lane = tid & 63;
  const int wn   = (tid >> 6) * 64;        // wave's N offset

  // staging: thread -> 16B chunk of a 64-elem row; source column XOR-permuted
  const int srow  = tid >> 3;              // 0..31
  const int sxcol = ((tid & 7) ^ (srow & 7)) * 8;   // global col (elements)
  const unsigned short* gW = Wm + ((size_t)b * 3 * 512 + o0) * 512;
  const unsigned short* gX = xT + ((size_t)b * TP + t0) * CIN;

  f32x4 acc[4][4];
  #pragma unroll
  for (int i = 0; i < 4; ++i)
    #pragma unroll
    for (int jj = 0; jj < 4; ++jj) acc[i][jj] = (f32x4){0.f, 0.f, 0.f, 0.f};

  for (int kk = 0; kk < 8; ++kk) {
    const int i0 = kk * 64;
    __syncthreads();                       // previous compute done
    // A: 3 taps x (2 x 32 rows)
    #pragma unroll
    for (int tap = 0; tap < 3; ++tap)
      #pragma unroll
      for (int p = 0; p < 2; ++p)
        __builtin_amdgcn_global_load_lds(
            (const __attribute__((address_space(1))) void*)
              (gW + (size_t)tap * 512 * 512 + (size_t)(p * 32 + srow) * 512 + i0 + sxcol),
            (__attribute__((address_space(3))) void*)(&lA[tap * 4096 + p * 2048 + tid * 8]),
            16, 0, 0);
    // B: 258 rows (t0-1 .. t0+256 in logical t; padded coords t0 .. t0+257)
    #pragma unroll
    for (int q = 0; q < 8; ++q)
      __builtin_amdgcn_global_load_lds(
          (const __attribute__((address_space(1))) void*)
            (gX + (size_t)(q * 32 + srow) * CIN + i0 + sxcol),
          (__attribute__((address_space(3))) void*)(&lB[(q * 256 + tid) * 8]),
          16, 0, 0);
    if (tid < 16)
      __builtin_amdgcn_global_load_lds(
          (const __attribute__((address_space(1))) void*)
            (gX + (size_t)(256 + srow) * CIN + i0 + sxcol),
          (__attribute__((address_space(3))) void*)(&lB[(2048 + tid) * 8]),
          16, 0, 0);
    __syncthreads();                       // staging visible

    #pragma unroll
    for (int k = 0; k < 3; ++k) {
      #pragma unroll
      for (int s = 0; s < 2; ++s) {
        const int kc = s * 4 + (lane >> 4);       // chunk index 0..7
        bf16x8 af[4], bfr[4];
        #pragma unroll
        for (int mi = 0; mi < 4; ++mi) {
          const int ra = mi * 16 + (lane & 15);
          af[mi] = *(const bf16x8*)&lA[k * 4096 + ra * 64 + ((kc ^ (ra & 7)) << 3)];
        }
        #pragma unroll
        for (int ni = 0; ni < 4; ++ni) {
          const int rb = wn + ni * 16 + (lane & 15) + k;
          bfr[ni] = *(const bf16x8*)&lB[rb * 64 + ((kc ^ (rb & 7)) << 3)];
        }
        #pragma unroll
        for (int mi = 0; mi < 4; ++mi)
          #pragma unroll
          for (int ni = 0; ni < 4; ++ni)
            acc[mi][ni] = __builtin_amdgcn_mfma_f32_16x16x32_bf16(af[mi], bfr[ni], acc[mi][ni], 0, 0, 0);
      }
    }
  }

  // epilogue: D row = (lane>>4)*4 + reg, col = lane&15 (m89 mapping)
  float* ob = out + ((size_t)b * COUT + o0) * T_ + t0 + wn;
  const int rrow = (lane >> 4) * 4;
  const int ccol = lane & 15;
  #pragma unroll
  for (int mi = 0; mi < 4; ++mi)
    #pragma unroll
    for (int ni = 0; ni < 4; ++ni)
      #pragma unroll
      for (int rr = 0; rr < 4; ++rr)
        ob[(size_t)(mi * 16 + rrow + rr) * T_ + ni * 16 + ccol] = acc[mi][ni][rr];
}

// ---------------------------------------------------------------------------
extern "C" void kernel_launch(void* const* d_in, const int* in_sizes, int n_in,
                              void* d_out, int out_size, void* d_ws, size_t ws_size,
                              hipStream_t stream) {
  const float* x       = (const float*)d_in[0];   // [16,512,2048]
  const float* c_src   = (const float*)d_in[1];   // [16,128]
  const float* c_trg   = (const float*)d_in[2];   // [16,128]
  const float* style_w = (const float*)d_in[3];   // [512,256]
  const float* style_b = (const float*)d_in[4];   // [512]
  const float* weight  = (const float*)d_in[5];   // [1,512,512,3]
  float* out = (float*)d_out;

  // workspace: s_buf fp32 [16][512] @0; Wm bf16 [16][3][512][512] @32768;
  //            xT bf16 [16][2050][512] @25198592
  char* ws = (char*)d_ws;
  float* s_buf          = (float*)ws;
  unsigned short* Wm    = (unsigned short*)(ws + 32768);
  unsigned short* xTbuf = (unsigned short*)(ws + 32768 + 25165824);

  style_kernel<<<dim3(8, 16), 256, 0, stream>>>(c_src, c_trg, style_w, style_b, s_buf);
  modw_kernel<<<dim3(COUT), 256, 0, stream>>>(weight, s_buf, Wm);
  transpose_kernel<<<dim3(T_ / 64, CIN / 64, B_), 256, 0, stream>>>(x, xTbuf);
  gemm_kernel<<<dim3(1024), 256, 0, stream>>>(Wm, xTbuf, out);
}

// Round 4
// 187.134 us; speedup vs baseline: 1.1349x; 1.0096x over previous
//
#include <hip/hip_runtime.h>
#include <cstdint>
#include <cstddef>

// ---------------------------------------------------------------------------
// Style2ResidualBlock1DSrc: modulated conv1d (StyleGAN2-style) on MI355X.
// bf16 MFMA GEMM pipeline. R3:
//  - gemm: wave tile 64x128 (was 64x64) -> LDS-read bytes/FLOP cut 25%
//    (measured bottleneck: 1.57 GB LDS reads @ 85 B/cyc/CU = 30us > 20.6us MFMA).
//  - gemm: BM=128 BN=256 BK=32, LDS 41.1 KB -> 2 blocks/CU, grid=512=2/CU exact.
//  - swizzle adapted to 32-wide rows: c ^ ((row>>1)&3) -> 2-way (free) frag reads.
// ---------------------------------------------------------------------------

#define LIN_SCALE  0.0625f           // 1/sqrt(256)
#define CONV_SCALE 0.014731391f      // 1/sqrt(512*9)

#define B_   16
#define CIN  512
#define COUT 512
#define T_   2048
#define TP   2050                    // T + 2 pad rows

typedef __bf16 bf16x8 __attribute__((ext_vector_type(8)));
typedef float  f32x4  __attribute__((ext_vector_type(4)));
typedef unsigned short u16x8 __attribute__((ext_vector_type(8)));
typedef unsigned short u16x2 __attribute__((ext_vector_type(2)));

#define AS1 __attribute__((address_space(1)))
#define AS3 __attribute__((address_space(3)))

__device__ inline unsigned short f2bf(float f) {
  __bf16 h = (__bf16)f;              // RNE fptrunc
  return __builtin_bit_cast(unsigned short, h);
}

// ---------------- 1. style linear: s[b][i] ----------------
__global__ __launch_bounds__(256) void style_kernel(const float* __restrict__ c_src,
                                                    const float* __restrict__ c_trg,
                                                    const float* __restrict__ sw,
                                                    const float* __restrict__ sb,
                                                    float* __restrict__ s) {
  __shared__ float c[256];
  const int b = blockIdx.y;
  const int tid = threadIdx.x;
  c[tid] = (tid < 128) ? c_src[b * 128 + tid] : c_trg[b * 128 + tid - 128];
  __syncthreads();
  const int w = tid >> 6, lane = tid & 63;
  #pragma unroll
  for (int rr = 0; rr < 16; ++rr) {
    const int i = blockIdx.x * 64 + w * 16 + rr;
    const float* row = sw + (size_t)i * 256;
    float acc = row[lane] * c[lane] + row[lane + 64] * c[lane + 64]
              + row[lane + 128] * c[lane + 128] + row[lane + 192] * c[lane + 192];
    #pragma unroll
    for (int off = 32; off; off >>= 1) acc += __shfl_down(acc, off, 64);
    if (lane == 0) s[b * 512 + i] = acc * LIN_SCALE + sb[i];
  }
}

// ---------------- 2. modulate + demodulate -> bf16 W[b][tap][o][i] ----------------
__global__ __launch_bounds__(256) void modw_kernel(const float* __restrict__ weight,
                                                   const float* __restrict__ s,
                                                   unsigned short* __restrict__ Wm) {
  const int o = blockIdx.x;
  const int tid = threadIdx.x;
  __shared__ float wsh[1536];        // weight[o][:][:]
  __shared__ float svs[16 * 512];    // all style vectors (32 KB)
  __shared__ float partial[16][4];
  __shared__ float demv[16];

  #pragma unroll
  for (int j = tid; j < 1536; j += 256) wsh[j] = weight[(size_t)o * 1536 + j];
  #pragma unroll
  for (int j = tid; j < 16 * 512; j += 256) svs[j] = s[j];
  __syncthreads();

  float wr[6];
  #pragma unroll
  for (int q = 0; q < 6; ++q) wr[q] = wsh[tid * 6 + q] * CONV_SCALE;

  const int lane = tid & 63, w = tid >> 6;
  float ssb[16];
  #pragma unroll
  for (int b = 0; b < 16; ++b) {
    const float s0 = svs[b * 512 + 2 * tid];
    const float s1 = svs[b * 512 + 2 * tid + 1];
    float ss = 0.f;
    #pragma unroll
    for (int q = 0; q < 3; ++q) { float v = wr[q] * s0; ss += v * v; }
    #pragma unroll
    for (int q = 3; q < 6; ++q) { float v = wr[q] * s1; ss += v * v; }
    ssb[b] = ss;
  }
  #pragma unroll
  for (int b = 0; b < 16; ++b) {
    float ss = ssb[b];
    #pragma unroll
    for (int off = 32; off; off >>= 1) ss += __shfl_down(ss, off, 64);
    if (lane == 0) partial[b][w] = ss;
  }
  __syncthreads();
  if (tid < 16)
    demv[tid] = rsqrtf(partial[tid][0] + partial[tid][1] + partial[tid][2] + partial[tid][3] + 1e-8f);
  __syncthreads();

  #pragma unroll
  for (int b = 0; b < 16; ++b) {
    const float dem = demv[b];
    const float s0 = svs[b * 512 + 2 * tid] * dem;
    const float s1 = svs[b * 512 + 2 * tid + 1] * dem;
    #pragma unroll
    for (int k = 0; k < 3; ++k) {
      u16x2 v;
      v.x = f2bf(wr[k] * s0);
      v.y = f2bf(wr[3 + k] * s1);
      *(u16x2*)&Wm[(((size_t)b * 3 + k) * 512 + o) * 512 + 2 * tid] = v;
    }
  }
}

// ---------------- 3. transpose + pad + bf16 (+ fused zpad) ----------------
__global__ __launch_bounds__(256) void transpose_kernel(const float* __restrict__ x,
                                                        unsigned short* __restrict__ xT) {
  __shared__ float tile[64][65];
  const int b = blockIdx.z, i0 = blockIdx.y * 64, t0 = blockIdx.x * 64;
  const int tid = threadIdx.x;

  const int lr = tid >> 4;            // 0..15
  const int lc = (tid & 15) * 4;      // float4
  const float* xb = x + ((size_t)b * CIN + i0) * T_ + t0;
  #pragma unroll
  for (int p = 0; p < 4; ++p) {
    const int r = p * 16 + lr;
    const float4 v = *(const float4*)(xb + (size_t)r * T_ + lc);
    tile[r][lc + 0] = v.x; tile[r][lc + 1] = v.y;
    tile[r][lc + 2] = v.z; tile[r][lc + 3] = v.w;
  }
  // fused zero-pad of rows 0 and 2049 (no barrier dependency)
  if (blockIdx.x == 0 && tid < 8)
    *(u16x8*)&xT[(size_t)b * TP * CIN + i0 + tid * 8] = (u16x8){0,0,0,0,0,0,0,0};
  if (blockIdx.x == gridDim.x - 1 && tid < 8)
    *(u16x8*)&xT[((size_t)b * TP + TP - 1) * CIN + i0 + tid * 8] = (u16x8){0,0,0,0,0,0,0,0};
  __syncthreads();

  const int st = tid >> 3;            // 0..31
  const int si = (tid & 7) * 8;       // 16B
  unsigned short* xTb = xT + ((size_t)b * TP + 1 + t0) * CIN + i0;
  #pragma unroll
  for (int p = 0; p < 2; ++p) {
    const int t = p * 32 + st;
    u16x8 v;
    #pragma unroll
    for (int q = 0; q < 8; ++q) v[q] = f2bf(tile[si + q][t]);
    *(u16x8*)&xTb[(size_t)t * CIN + si] = v;
  }
}

// ---------------- 4. main GEMM, tap-fused, wave tile 64x128 ----------------
// out[b][o0..+128][t0..+256] = sum_{tap,i} Wm[b][tap][o][i] * xT[b][t0+lt+tap][i]
// BK=32. LDS: lA[3][128][32], lB[258][32], both chunk-swizzled c^((row>>1)&3).
// 4 waves in 2(M)x2(N) grid, each 64x128 via 4x8 16x16x32 frags.
#define BM 128
#define BN 256
#define BK 32

__global__ __launch_bounds__(256, 2) void gemm_kernel(const unsigned short* __restrict__ Wm,
                                                      const unsigned short* __restrict__ xT,
                                                      float* __restrict__ out) {
  __shared__ unsigned short lA[3 * 128 * 32];   // 24576 B
  __shared__ unsigned short lB[258 * 32];       // 16512 B

  // XCD b-grouping: 512 blocks; ids == xcd (mod 8); 2 batches per XCD.
  const int id  = blockIdx.x;
  const int xcd = id & 7;
  const int j   = id >> 3;                 // 0..63
  const int b   = xcd + 8 * (j >> 5);      // 0..15
  const int r   = j & 31;
  const int o0  = (r >> 3) * BM;           // 4 o-blocks
  const int t0  = (r & 7) * BN;            // 8 t-blocks

  const int tid  = threadIdx.x;
  const int lane = tid & 63;
  const int wm   = ((tid >> 6) & 1) * 64;  // wave M offset
  const int wn   = (tid >> 7) * 128;       // wave N offset
  const int rl   = lane & 15;
  const int kc   = lane >> 4;              // chunk 0..3 within 32-wide row

  const unsigned short* gW = Wm + ((size_t)b * 3 * 512 + o0) * 512;
  const unsigned short* gX = xT + ((size_t)b * TP + t0) * CIN;

  f32x4 acc[4][8];
  #pragma unroll
  for (int i = 0; i < 4; ++i)
    #pragma unroll
    for (int jj = 0; jj < 8; ++jj) acc[i][jj] = (f32x4){0.f, 0.f, 0.f, 0.f};

  for (int kk = 0; kk < 16; ++kk) {
    const int i0 = kk * 32;
    __syncthreads();                       // previous compute done
    // A: 1536 16B-chunks, 6 per thread. chunk ci=(tap*128+ar)*4+c
    #pragma unroll
    for (int q = 0; q < 6; ++q) {
      const int ci  = q * 256 + tid;
      const int row = ci >> 2;             // tap*128 + ar
      const int tap = row >> 7;
      const int ar  = row & 127;
      const int gc  = ((ci & 3) ^ ((ar >> 1) & 3)) * 8;
      __builtin_amdgcn_global_load_lds(
          (const AS1 void*)(gW + (size_t)tap * 262144 + (size_t)ar * 512 + i0 + gc),
          (AS3 void*)(&lA[ci * 8]), 16, 0, 0);
    }
    // B: 258 rows x 4 chunks = 1032; 4 per thread + tail 8
    #pragma unroll
    for (int q = 0; q < 4; ++q) {
      const int ci  = q * 256 + tid;
      const int row = ci >> 2;
      const int gc  = ((ci & 3) ^ ((row >> 1) & 3)) * 8;
      __builtin_amdgcn_global_load_lds(
          (const AS1 void*)(gX + (size_t)row * CIN + i0 + gc),
          (AS3 void*)(&lB[ci * 8]), 16, 0, 0);
    }
    if (tid < 8) {
      const int ci  = 1024 + tid;
      const int row = ci >> 2;             // 256, 257
      const int gc  = ((ci & 3) ^ ((row >> 1) & 3)) * 8;
      __builtin_amdgcn_global_load_lds(
          (const AS1 void*)(gX + (size_t)row * CIN + i0 + gc),
          (AS3 void*)(&lB[ci * 8]), 16, 0, 0);
    }
    __syncthreads();                       // staging visible

    #pragma unroll
    for (int tap = 0; tap < 3; ++tap) {
      bf16x8 af[4], bfr[8];
      #pragma unroll
      for (int mi = 0; mi < 4; ++mi) {
        const int ra = wm + mi * 16 + rl;
        af[mi] = *(const bf16x8*)&lA[((tap * 128 + ra) * 4 + (kc ^ ((ra >> 1) & 3))) * 8];
      }
      #pragma unroll
      for (int ni = 0; ni < 8; ++ni) {
        const int rb = wn + ni * 16 + rl + tap;
        bfr[ni] = *(const bf16x8*)&lB[(rb * 4 + (kc ^ ((rb >> 1) & 3))) * 8];
      }
      #pragma unroll
      for (int mi = 0; mi < 4; ++mi)
        #pragma unroll
        for (int ni = 0; ni < 8; ++ni)
          acc[mi][ni] = __builtin_amdgcn_mfma_f32_16x16x32_bf16(af[mi], bfr[ni], acc[mi][ni], 0, 0, 0);
    }
  }

  // epilogue: D row = (lane>>4)*4 + reg, col = lane&15 (m89 mapping)
  float* ob = out + ((size_t)b * COUT + o0 + wm) * T_ + t0 + wn;
  const int rrow = (lane >> 4) * 4;
  const int ccol = lane & 15;
  #pragma unroll
  for (int mi = 0; mi < 4; ++mi)
    #pragma unroll
    for (int ni = 0; ni < 8; ++ni)
      #pragma unroll
      for (int rr = 0; rr < 4; ++rr)
        ob[(size_t)(mi * 16 + rrow + rr) * T_ + ni * 16 + ccol] = acc[mi][ni][rr];
}

// ---------------------------------------------------------------------------
extern "C" void kernel_launch(void* const* d_in, const int* in_sizes, int n_in,
                              void* d_out, int out_size, void* d_ws, size_t ws_size,
                              hipStream_t stream) {
  const float* x       = (const float*)d_in[0];   // [16,512,2048]
  const float* c_src   = (const float*)d_in[1];   // [16,128]
  const float* c_trg   = (const float*)d_in[2];   // [16,128]
  const float* style_w = (const float*)d_in[3];   // [512,256]
  const float* style_b = (const float*)d_in[4];   // [512]
  const float* weight  = (const float*)d_in[5];   // [1,512,512,3]
  float* out = (float*)d_out;

  // workspace: s_buf fp32 [16][512] @0; Wm bf16 [16][3][512][512] @32768;
  //            xT bf16 [16][2050][512] @25198592
  char* ws = (char*)d_ws;
  float* s_buf          = (float*)ws;
  unsigned short* Wm    = (unsigned short*)(ws + 32768);
  unsigned short* xTbuf = (unsigned short*)(ws + 32768 + 25165824);

  style_kernel<<<dim3(8, 16), 256, 0, stream>>>(c_src, c_trg, style_w, style_b, s_buf);
  modw_kernel<<<dim3(COUT), 256, 0, stream>>>(weight, s_buf, Wm);
  transpose_kernel<<<dim3(T_ / 64, CIN / 64, B_), 256, 0, stream>>>(x, xTbuf);
  gemm_kernel<<<dim3(512), 256, 0, stream>>>(Wm, xTbuf, out);
}